// Round 6
// baseline (305.274 us; speedup 1.0000x reference)
//
#include <hip/hip_runtime.h>
#include <math.h>

#define NBINS 28
#define L2E 1.44269504088896340736f

#define EXP2F(x) __builtin_amdgcn_exp2f(x)
#define RCPF(x)  __builtin_amdgcn_rcpf(x)

// workspace float offsets.  ROW-MAJOR, prescaled (proven R1 layout):
//   WS_W1[f*16+j] = W1[f][j] * -log2e     (f=0..7,  j=0..15)
//   WS_W2[k*16+j] = W2[k][j] * -log2e     (k=0..15, j=0..15)
// Weights are wave-uniform -> compiler scalarizes into SGPRs (K$ path).
// R6 lesson-in-progress: NO sched_barriers in the main loop — they
// forbade s_load prefetch under math (sched_barrier(0) blocks ALL
// movement), serializing 27 lgkm waits per pair.  Let the scheduler
// software-pipeline the scalar loads; SGPR pressure bounds the hoist.
#define WS_TBL 0    // 40 floats: ml_table[d-1] = exp(ml_mlp(d) - 0.25 d), d=1..40
#define WS_W1  64   // 128 floats, row-major, * -log2e
#define WS_B1  192  // 16, * -log2e
#define WS_W2  208  // 256 floats, row-major, * -log2e
#define WS_B2  464  // 16, * -log2e
#define WS_W3  480  // 16, * +log2e
#define WS_B3  496  // 1, * +log2e
#define WS_TOT 512

__global__ void prep_kernel(const float* __restrict__ mh_W1, const float* __restrict__ mh_b1,
                            const float* __restrict__ mh_W2, const float* __restrict__ mh_b2,
                            const float* __restrict__ mh_W3, const float* __restrict__ mh_b3,
                            const float* __restrict__ ml_W1, const float* __restrict__ ml_b1,
                            const float* __restrict__ ml_W2, const float* __restrict__ ml_b2,
                            const float* __restrict__ ml_W3, const float* __restrict__ ml_b3,
                            float* __restrict__ ws, float* __restrict__ out_bins) {
    const int t = threadIdx.x;  // 64 threads
    for (int k = t; k < 128; k += 64) ws[WS_W1 + k] = -L2E * mh_W1[k];
    for (int k = t; k < 16;  k += 64) ws[WS_B1 + k] = -L2E * mh_b1[k];
    for (int k = t; k < 256; k += 64) ws[WS_W2 + k] = -L2E * mh_W2[k];
    for (int k = t; k < 16;  k += 64) ws[WS_B2 + k] = -L2E * mh_b2[k];
    for (int k = t; k < 16;  k += 64) ws[WS_W3 + k] =  L2E * mh_W3[k];
    if (t == 0) ws[WS_B3] = L2E * mh_b3[0];

    if (t < 40) {
        const float x = (float)(t + 1);
        float h1[16], h2[16];
        #pragma unroll
        for (int j = 0; j < 16; ++j)
            h1[j] = 1.0f / (1.0f + expf(-(x * ml_W1[j] + ml_b1[j])));
        #pragma unroll
        for (int j = 0; j < 16; ++j) {
            float a = ml_b2[j];
            #pragma unroll
            for (int k = 0; k < 16; ++k) a = fmaf(h1[k], ml_W2[k * 16 + j], a);
            h2[j] = 1.0f / (1.0f + expf(-a));
        }
        float phi = ml_b3[0];
        #pragma unroll
        for (int k = 0; k < 16; ++k) phi = fmaf(h2[k], ml_W3[k], phi);
        const float sc = expf(phi - 0.25f * x);
        ws[WS_TBL + t] = sc;
        if (t < NBINS) out_bins[t] = sc;  // dl2_scores term of output 1
    }
}

// 4 rows/thread, rows innermost so each wave-uniform weight s_load feeds
// 4 scalar FMAs (R1 fed 2).  Scalar fmaf math identical to the verified
// R1 body; I/O skeleton identical to the verified R3 (int4/float4, quad
// indexing).  All register arrays statically indexed under full unroll.
__global__ __launch_bounds__(256) void main_kernel(
        const float4* __restrict__ x4,
        const int4* __restrict__ dl4p,
        const int4* __restrict__ ml4p,
        const float* __restrict__ ws,
        float4* __restrict__ out4,
        float* __restrict__ out_bins,
        int nquad) {
    __shared__ float s_tbl[40];
    __shared__ float s_bins[4 * NBINS];
    const int tid = threadIdx.x;
    if (tid < 40) s_tbl[tid] = ws[WS_TBL + tid];
    if (tid < 4 * NBINS) s_bins[tid] = 0.0f;
    __syncthreads();

    const int q = blockIdx.x * 256 + tid;
    const bool active = (q < nquad);
    const int qc = active ? q : 0;   // clamp loads; discard via `active` at store

    float xf[4][8];
    #pragma unroll
    for (int r = 0; r < 4; ++r) {
        const float4 a = x4[8 * qc + 2 * r + 0];
        const float4 b = x4[8 * qc + 2 * r + 1];
        xf[r][0] = a.x; xf[r][1] = a.y; xf[r][2] = a.z; xf[r][3] = a.w;
        xf[r][4] = b.x; xf[r][5] = b.y; xf[r][6] = b.z; xf[r][7] = b.w;
    }
    const int4 dl = dl4p[qc];
    const int4 ml = ml4p[qc];
    const int dlv[4] = {dl.x, dl.y, dl.z, dl.w};
    const int mlv[4] = {ml.x, ml.y, ml.z, ml.w};

    // ---- layer 1: 8 -> 16 (weights prescaled by -log2e, SGPR-resident) ----
    float u[4][16];
    #pragma unroll
    for (int j = 0; j < 16; ++j) {
        const float b = ws[WS_B1 + j];
        #pragma unroll
        for (int r = 0; r < 4; ++r) u[r][j] = b;
    }
    #pragma unroll
    for (int f = 0; f < 8; ++f) {
        #pragma unroll
        for (int j = 0; j < 16; ++j) {
            const float w = ws[WS_W1 + f * 16 + j];
            #pragma unroll
            for (int r = 0; r < 4; ++r) u[r][j] = fmaf(xf[r][f], w, u[r][j]);
        }
    }
    float h[4][16];
    #pragma unroll
    for (int j = 0; j < 16; ++j) {
        #pragma unroll
        for (int r = 0; r < 4; ++r) h[r][j] = RCPF(1.0f + EXP2F(u[r][j]));
    }

    // ---- layer 2: 16 -> 16 ----
    float v[4][16];
    #pragma unroll
    for (int j = 0; j < 16; ++j) {
        const float b = ws[WS_B2 + j];
        #pragma unroll
        for (int r = 0; r < 4; ++r) v[r][j] = b;
    }
    #pragma unroll
    for (int k = 0; k < 16; ++k) {
        #pragma unroll
        for (int j = 0; j < 16; ++j) {
            const float w = ws[WS_W2 + k * 16 + j];
            #pragma unroll
            for (int r = 0; r < 4; ++r) v[r][j] = fmaf(h[r][k], w, v[r][j]);
        }
    }

    // ---- layer 3 + psi ----
    const float pb = ws[WS_B3];          // prescaled by +log2e
    float phi[4] = {pb, pb, pb, pb};
    #pragma unroll
    for (int j = 0; j < 16; ++j) {
        const float w3 = ws[WS_W3 + j];  // prescaled by +log2e
        #pragma unroll
        for (int r = 0; r < 4; ++r)
            phi[r] = fmaf(RCPF(1.0f + EXP2F(v[r][j])), w3, phi[r]);
    }
    float sc[4];
    #pragma unroll
    for (int r = 0; r < 4; ++r)
        sc[r] = EXP2F(fmaf((float)dlv[r], -0.25f * L2E, phi[r]));

    // ---- epilogue ----
    if (active) {
        float ov[4];
        #pragma unroll
        for (int r = 0; r < 4; ++r) {
            const int i = min(max(dlv[r], 1), 40) - 1;
            ov[r] = sc[r] + ((dlv[r] == mlv[r]) ? s_tbl[i] : 0.0f);
        }
        float4 o; o.x = ov[0]; o.y = ov[1]; o.z = ov[2]; o.w = ov[3];
        out4[q] = o;
        float* myb = &s_bins[(tid >> 6) * NBINS];
        #pragma unroll
        for (int r = 0; r < 4; ++r)
            if (dlv[r] >= 1 && dlv[r] <= NBINS)
                unsafeAtomicAdd(&myb[dlv[r] - 1], sc[r]);
    }

    __syncthreads();
    if (tid < NBINS) {
        const float bsum = s_bins[tid] + s_bins[NBINS + tid] +
                           s_bins[2 * NBINS + tid] + s_bins[3 * NBINS + tid];
        unsafeAtomicAdd(&out_bins[tid], bsum);
    }
}

extern "C" void kernel_launch(void* const* d_in, const int* in_sizes, int n_in,
                              void* d_out, int out_size, void* d_ws, size_t ws_size,
                              hipStream_t stream) {
    const int n = in_sizes[0] / 8;  // N rows (N = 4e6, divisible by 4)

    const float* x_feat = (const float*)d_in[0];
    const float* mh_W1  = (const float*)d_in[1];
    const float* mh_b1  = (const float*)d_in[2];
    const float* mh_W2  = (const float*)d_in[3];
    const float* mh_b2  = (const float*)d_in[4];
    const float* mh_W3  = (const float*)d_in[5];
    const float* mh_b3  = (const float*)d_in[6];
    const float* ml_W1  = (const float*)d_in[7];
    const float* ml_b1  = (const float*)d_in[8];
    const float* ml_W2  = (const float*)d_in[9];
    const float* ml_b2  = (const float*)d_in[10];
    const float* ml_W3  = (const float*)d_in[11];
    const float* ml_b3  = (const float*)d_in[12];
    const int* del_lens = (const int*)d_in[13];
    const int* mh_len   = (const int*)d_in[14];

    float* out      = (float*)d_out;
    float* out_bins = out + n;  // last 28 elements of d_out
    float* ws       = (float*)d_ws;

    prep_kernel<<<dim3(1), dim3(64), 0, stream>>>(
        mh_W1, mh_b1, mh_W2, mh_b2, mh_W3, mh_b3,
        ml_W1, ml_b1, ml_W2, ml_b2, ml_W3, ml_b3,
        ws, out_bins);

    const int nquad = n / 4;
    const int nblocks = (nquad + 255) / 256;
    main_kernel<<<dim3(nblocks), dim3(256), 0, stream>>>(
        (const float4*)x_feat, (const int4*)del_lens, (const int4*)mh_len,
        ws, (float4*)out, out_bins, nquad);
}